// Round 1
// baseline (983.048 us; speedup 1.0000x reference)
//
#include <hip/hip_runtime.h>

typedef float  float4v __attribute__((ext_vector_type(4)));
typedef short  short8  __attribute__((ext_vector_type(8)));

__device__ __forceinline__ unsigned short f2bf(float f) {
    unsigned int u = __float_as_uint(f);
    u += 0x7fffu + ((u >> 16) & 1u);   // RNE
    return (unsigned short)(u >> 16);
}

// ---- kernel 0: weights fp32 [k][c][r][s] -> bf16 [k][r][s][c] in d_ws ----
__global__ void wt_transform(const float* __restrict__ w, unsigned short* __restrict__ wt) {
    int idx = blockIdx.x * 256 + threadIdx.x;      // 256*9*128 = 294912 total
    int c  = idx & 127;
    int t  = idx >> 7;          // (k*3+r)*3+s
    int s  = t % 3;
    int kr = t / 3;
    int r  = kr % 3;
    int k  = kr / 3;
    wt[idx] = f2bf(w[((size_t)(k * 128 + c)) * 9 + r * 3 + s]);
}

// ---- main kernel: implicit-GEMM conv, M=outch(128/block), N=pixels(2 rows x 112) ----
__global__ __launch_bounds__(256, 2) void conv_mfma(
    const float* __restrict__ in, const unsigned short* __restrict__ wt,
    const float* __restrict__ bias, float* __restrict__ out)
{
    // stride 40 (=32c + 8 pad): rows 80B apart -> b128 frag reads 16B-aligned, ~2-way bank aliasing (free)
    __shared__ __align__(16) unsigned short s_in[2 * 114 * 40];  // 18,240 B
    __shared__ __align__(16) unsigned short s_w [3 * 128 * 40];  // 30,720 B

    const int tid    = threadIdx.x;
    const int lane   = tid & 63;
    const int wv     = tid >> 6;
    const int wave_m = wv >> 1;     // 0..1: which 64 outch
    const int p      = wv & 1;      // 0..1: which output row of the pair
    const int l15    = lane & 15;
    const int quad   = lane >> 4;

    const int k0    = blockIdx.x * 128;   // outch base (2 halves)
    const int hb    = blockIdx.y * 2;     // output row pair base (56 pairs)
    const int n_idx = blockIdx.z;         // batch (32)

    float4v acc[4][7];
#pragma unroll
    for (int a = 0; a < 4; ++a)
#pragma unroll
        for (int t = 0; t < 7; ++t)
            acc[a][t] = (float4v){0.f, 0.f, 0.f, 0.f};

    const float* in_n = in + (size_t)n_idx * 128 * 112 * 112;

    for (int r = 0; r < 3; ++r) {
        for (int c0 = 0; c0 < 128; c0 += 32) {
            __syncthreads();
            // ---- stage input: 2 rows x 114 wi x 32 c, 4 c per thread-slot ----
#pragma unroll
            for (int i = 0; i < 8; ++i) {
                int flat = tid + i * 256;              // < 1824 = 114*2*8
                if (flat < 1824) {
                    int wi   = flat % 114;
                    int rest = flat / 114;
                    int row2 = rest & 1;
                    int cg   = rest >> 1;              // 0..7
                    int h_in = hb + row2 + r - 1;
                    int w    = wi - 1;
                    bool ok  = (h_in >= 0) && (h_in < 112) && (w >= 0) && (w < 112);
                    const float* src = in_n + ((size_t)(c0 + cg * 4) * 112 + (ok ? h_in : 0)) * 112
                                            + (ok ? w : 0);
                    float v0 = ok ? src[0]         : 0.f;
                    float v1 = ok ? src[12544]     : 0.f;
                    float v2 = ok ? src[2 * 12544] : 0.f;
                    float v3 = ok ? src[3 * 12544] : 0.f;
                    uint2 pk;
                    pk.x = (unsigned)f2bf(v0) | ((unsigned)f2bf(v1) << 16);
                    pk.y = (unsigned)f2bf(v2) | ((unsigned)f2bf(v3) << 16);
                    *(uint2*)&s_in[(row2 * 114 + wi) * 40 + cg * 4] = pk;
                }
            }
            // ---- stage weights: [3 s][128 kk][32 c], 8 c per thread-slot, b128 copy from d_ws ----
#pragma unroll
            for (int i = 0; i < 6; ++i) {
                int flat = tid + i * 256;              // exactly 1536 = 128*3*4
                int co8  = flat & 3;
                int s    = (flat >> 2) % 3;
                int kk   = flat / 12;
                const uint4 v = *(const uint4*)&wt[((size_t)(k0 + kk) * 9 + r * 3 + s) * 128
                                                  + c0 + co8 * 8];
                *(uint4*)&s_w[(s * 128 + kk) * 40 + co8 * 8] = v;
            }
            __syncthreads();
            // ---- compute: 3 s x (4 A-frags + 7x(1 B-frag + 4 MFMA)) ----
#pragma unroll
            for (int s = 0; s < 3; ++s) {
                short8 af[4];
#pragma unroll
                for (int a = 0; a < 4; ++a)
                    af[a] = *(const short8*)&s_w[(s * 128 + wave_m * 64 + a * 16 + l15) * 40
                                                 + quad * 8];
#pragma unroll
                for (int t = 0; t < 7; ++t) {
                    short8 bf = *(const short8*)&s_in[(p * 114 + t * 16 + l15 + s) * 40 + quad * 8];
#pragma unroll
                    for (int a = 0; a < 4; ++a)
                        acc[a][t] = __builtin_amdgcn_mfma_f32_16x16x32_bf16(af[a], bf, acc[a][t],
                                                                            0, 0, 0);
                }
            }
        }
    }

    // ---- epilogue: D col = lane&15 = w (coalesced), row = quad*4+reg = outch ----
    const int h_out = hb + p;
#pragma unroll
    for (int a = 0; a < 4; ++a) {
        int kk = k0 + wave_m * 64 + a * 16 + quad * 4;
        float b0 = bias[kk + 0], b1 = bias[kk + 1], b2 = bias[kk + 2], b3 = bias[kk + 3];
#pragma unroll
        for (int t = 0; t < 7; ++t) {
            int wcol = t * 16 + l15;
            size_t base = (((size_t)n_idx * 256 + kk) * 112 + h_out) * 112 + wcol;
            out[base]             = acc[a][t][0] + b0;
            out[base + 12544]     = acc[a][t][1] + b1;
            out[base + 2 * 12544] = acc[a][t][2] + b2;
            out[base + 3 * 12544] = acc[a][t][3] + b3;
        }
    }
}

// ---- fallback (only if ws too small for transformed weights): naive fp32 direct conv ----
__global__ void conv_naive(const float* __restrict__ in, const float* __restrict__ w,
                           const float* __restrict__ bias, float* __restrict__ out) {
    size_t idx = (size_t)blockIdx.x * 256 + threadIdx.x;
    if (idx >= (size_t)32 * 256 * 112 * 112) return;
    int wo = (int)(idx % 112);
    size_t t = idx / 112;
    int ho = (int)(t % 112); t /= 112;
    int k  = (int)(t % 256);
    int n  = (int)(t / 256);
    float acc = bias[k];
    for (int c = 0; c < 128; ++c)
        for (int r = 0; r < 3; ++r) {
            int hi = ho + r - 1;
            if (hi < 0 || hi >= 112) continue;
            for (int s = 0; s < 3; ++s) {
                int wi = wo + s - 1;
                if (wi < 0 || wi >= 112) continue;
                acc += in[((size_t)(n * 128 + c) * 112 + hi) * 112 + wi]
                     * w[((size_t)(k * 128 + c)) * 9 + r * 3 + s];
            }
        }
    out[idx] = acc;
}

extern "C" void kernel_launch(void* const* d_in, const int* in_sizes, int n_in,
                              void* d_out, int out_size, void* d_ws, size_t ws_size,
                              hipStream_t stream) {
    const float* in   = (const float*)d_in[0];
    const float* w    = (const float*)d_in[1];
    const float* bias = (const float*)d_in[2];
    float* out        = (float*)d_out;

    if (ws_size >= 294912 * sizeof(unsigned short)) {
        unsigned short* wt = (unsigned short*)d_ws;
        wt_transform<<<1152, 256, 0, stream>>>(w, wt);
        dim3 grid(2, 56, 32);
        conv_mfma<<<grid, dim3(256), 0, stream>>>(in, wt, bias, out);
    } else {
        size_t total = (size_t)32 * 256 * 112 * 112;
        conv_naive<<<(unsigned)((total + 255) / 256), 256, 0, stream>>>(in, w, bias, out);
    }
}